// Round 5
// baseline (129.638 us; speedup 1.0000x reference)
//
#include <hip/hip_runtime.h>
#include <hip/hip_bf16.h>

// GAT layer: B=8, N=2048, Fin=256, Fout=128  (f32 in / f32 out)
// Wh = h@W ; s1 = Wh@a1 ; s2 = Wh@a2
// P[i,j] = softmax_i( lrelu(s1_i+s2_j) ) ; out = elu(P @ Wh)
//
// R18 (= R17 hardened; R17 bench was an infra failure, no verdict):
// ALGORITHMIC rewrite — attention is rank-separable around the lrelu
// branch. With shat = LOG2E*s:  f(e_ij) = 2^(shat1_i) * 2^(shat2_j) if e>=0
// else 2^(a*shat1_i) * 2^(a*shat2_j); branch <=> shat2_j >= -shat1_i, a
// threshold in sorted-shat2 order. So:
//   Z_j     = 2^s2j * SufE[phi_j] + 2^(a*s2j) * PreA[phi_j]     (sorted s1)
//   out[i,:]= 2^s1i * S[theta_i,:] + 2^(a*s1i) * T[theta_i,:]   (sorted s2)
// where S/T = suffix/prefix scans of c1_j*Wh[j,:] / c2_j*Wh[j,:],
// c1=2^s2j/Z_j, c2=2^(a*s2j)/Z_j. O(N^2 D) -> O(N (logN + D)).
// Evidence: R13-R16 (4 structurally different O(N^2) pipelines) all land
// 101-105us -> fixed harness cost dominates; only algorithmic work removal
// can move the total. P is now exact f32 (error source = bf16 Wh only).
// R18 hardening vs R17: int4 staging (no float-punned int loads), no forced
// unroll on the Wh staging loop, structured else instead of early return.

#define ALPHA 0.2f
#define LOG2E 1.4426950408889634f
constexpr int Bb=8, Nn=2048, FIN=256, FOUT=128;
constexpr int NC=32, CH=64;          // chunks per batch, chunk size
constexpr int SUFSTR=2052;           // padded per-batch stride (16B aligned)

typedef __attribute__((ext_vector_type(8))) short short8;
typedef __attribute__((ext_vector_type(4))) float f32x4;
typedef const __attribute__((address_space(1))) unsigned int* gptr_t;
typedef __attribute__((address_space(3))) unsigned int* lptr_t;

__device__ __forceinline__ unsigned short bfbits(float x){
    __hip_bfloat16 h = __float2bfloat16(x);
    return *(unsigned short*)&h;
}
__device__ __forceinline__ float bf2f(unsigned short u){
    unsigned int w = ((unsigned int)u) << 16;
    return *(float*)&w;
}

// ---- K1: Wh = h@W via MFMA -> s1,s2 (xLOG2E) + Wh bf16 row-major ----
__global__ __launch_bounds__(256) void k_wh(const float* __restrict__ h,
                                            const float* __restrict__ W,
                                            const float* __restrict__ a,
                                            float* __restrict__ s1h,
                                            float* __restrict__ s2h,
                                            __hip_bfloat16* __restrict__ Whb){
    const int blk = blockIdx.x;            // 512
    const int rowbase = blk * 32;
    const int t = threadIdx.x;
    const int wave = t>>6, lane = t&63;
    const int wm = wave & 1, wn = wave >> 1;
    const int lm = lane & 15, q = lane >> 4;

    __shared__ __align__(16) float hs[32*260];      // 33.3 KB
    __shared__ __align__(16) float tt2[32][132];    // 16.9 KB
    __shared__ float s1red[2][32], s2red[2][32];

    {   // DMA h rows: wave w stages rows w*8..w*8+7
        const float* srcbase = h + (size_t)rowbase*FIN;
        #pragma unroll
        for (int c = 0; c < 8; ++c){
            const int row = wave*8 + c;
            __builtin_amdgcn_global_load_lds(
                (gptr_t)(srcbase + (size_t)row*FIN + lane*4),
                (lptr_t)&hs[row*260], 16, 0, 0);
        }
    }
    __syncthreads();

    f32x4 acc[4];
    #pragma unroll
    for (int ntl = 0; ntl < 4; ++ntl) acc[ntl] = (f32x4){0.f,0.f,0.f,0.f};

    const float* hrow = &hs[(wm*16 + lm)*260];
    const float* Wq   = W + (size_t)(q*8)*FOUT + wn*64 + lm;
    #pragma unroll
    for (int kt = 0; kt < 8; ++kt){
        float av[8];
        *(float4*)&av[0] = *(const float4*)&hrow[kt*32 + q*8];
        *(float4*)&av[4] = *(const float4*)&hrow[kt*32 + q*8 + 4];
        short8 afr;
        #pragma unroll
        for (int e = 0; e < 8; ++e) afr[e] = (short)bfbits(av[e]);
        const float* Wkt = Wq + (size_t)kt*32*FOUT;
        #pragma unroll
        for (int ntl = 0; ntl < 4; ++ntl){
            const float* Wp = Wkt + ntl*16;
            short8 bfr;
            #pragma unroll
            for (int e = 0; e < 8; ++e) bfr[e] = (short)bfbits(Wp[(size_t)e*FOUT]);
            acc[ntl] = __builtin_amdgcn_mfma_f32_16x16x32_bf16(afr, bfr, acc[ntl], 0,0,0);
        }
    }

    {   // s1/s2 partials over this wave's 64 cols, lm-reduce
        float a1v[4], a2v[4];
        #pragma unroll
        for (int ntl = 0; ntl < 4; ++ntl){
            a1v[ntl] = a[wn*64 + ntl*16 + lm];
            a2v[ntl] = a[FOUT + wn*64 + ntl*16 + lm];
        }
        #pragma unroll
        for (int rg = 0; rg < 4; ++rg){
            float p1 = 0.f, p2 = 0.f;
            #pragma unroll
            for (int ntl = 0; ntl < 4; ++ntl){
                p1 += acc[ntl][rg]*a1v[ntl];
                p2 += acc[ntl][rg]*a2v[ntl];
            }
            #pragma unroll
            for (int m = 1; m < 16; m <<= 1){
                p1 += __shfl_xor(p1, m);
                p2 += __shfl_xor(p2, m);
            }
            if (lm == 0){
                s1red[wn][wm*16 + q*4 + rg] = p1;
                s2red[wn][wm*16 + q*4 + rg] = p2;
            }
        }
    }

    // acc -> tt2 f32 tile [row][d]  (C layout 16x16x32: row=wm*16+q*4+rg)
    #pragma unroll
    for (int ntl = 0; ntl < 4; ++ntl)
        #pragma unroll
        for (int rg = 0; rg < 4; ++rg)
            tt2[wm*16 + q*4 + rg][wn*64 + ntl*16 + lm] = acc[ntl][rg];
    __syncthreads();

    if (t < 32){
        s1h[rowbase + t] = (s1red[0][t] + s1red[1][t]) * LOG2E;
        s2h[rowbase + t] = (s2red[0][t] + s2red[1][t]) * LOG2E;
    }
    {   // coalesced bf16 row write: thread = (row: t>>3) x (16-d seg: t&7)
        const int row = t >> 3, seg = (t & 7) * 16;
        const float* src = &tt2[row][seg];
        short8 v0, v1;
        #pragma unroll
        for (int e = 0; e < 8; ++e){
            v0[e] = (short)bfbits(src[e]);
            v1[e] = (short)bfbits(src[e+8]);
        }
        short* dst = (short*)Whb + (size_t)(rowbase + row)*FOUT + seg;
        *(short8*)dst       = v0;
        *(short8*)(dst + 8) = v1;
    }
}

// ---- K2: per batch, bitonic sort (blocks 0-7: s2+perm; 8-15: s1+iperm
//      then SufE/PreA scans of 2^s1s / 2^(a*s1s)) ----
__global__ __launch_bounds__(1024) void k_sort(const float* __restrict__ s1h,
                                               const float* __restrict__ s2h,
                                               float* __restrict__ s1s,
                                               float* __restrict__ s2s,
                                               int* __restrict__ ipr,
                                               int* __restrict__ prm,
                                               float* __restrict__ SufE,
                                               float* __restrict__ PreA){
    const int bb = blockIdx.x;      // 16
    const bool isS1 = bb >= 8;
    const int b = bb & 7;
    const int t = threadIdx.x;
    __shared__ __align__(16) float key[2048];
    __shared__ __align__(16) int   pay[2048];
    __shared__ __align__(16) float scb[2048];

    const float* src = (isS1 ? s1h : s2h) + (size_t)b*Nn;
    #pragma unroll
    for (int v=0; v<2; ++v){ const int i=t+v*1024; key[i]=src[i]; pay[i]=i; }
    __syncthreads();
    for (int k=2; k<=2048; k<<=1){
        for (int j=k>>1; j>0; j>>=1){
            const int i = ((t & ~(j-1))<<1) | (t & (j-1));
            const int l = i | j;
            const bool up = (i & k)==0;
            const float a0=key[i], a1=key[l];
            const bool sw = up ? (a0>a1) : (a0<a1);
            if (sw){
                key[i]=a1; key[l]=a0;
                const int p0=pay[i]; pay[i]=pay[l]; pay[l]=p0;
            }
            __syncthreads();
        }
    }
    {
        float* kdst = (isS1 ? s1s : s2s) + (size_t)b*Nn;
        int*   pdst = (isS1 ? ipr : prm) + (size_t)b*Nn;
        #pragma unroll
        for (int v=0; v<2; ++v){ const int i=t+v*1024; kdst[i]=key[i]; pdst[i]=pay[i]; }
    }
    if (isS1){
        __syncthreads();                 // pay now reusable as float buf
        float* bufB = (float*)pay;
        float* bufC = scb;

        // PreA: exclusive prefix of 2^(ALPHA*s1s)
        #pragma unroll
        for (int v=0; v<2; ++v){ const int i=t+v*1024; bufB[i]=__builtin_amdgcn_exp2f(ALPHA*key[i]); }
        __syncthreads();
        {
            float *sp=bufB, *dp=bufC;
            for (int off=1; off<2048; off<<=1){
                #pragma unroll
                for (int v=0; v<2; ++v){
                    const int i=t+v*1024;
                    float x = sp[i];
                    if (i>=off) x += sp[i-off];
                    dp[i]=x;
                }
                __syncthreads();
                float* tmp=sp; sp=dp; dp=tmp;
            }
            float* dst = PreA + (size_t)b*SUFSTR;
            #pragma unroll
            for (int v=0; v<2; ++v){ const int i=t+v*1024; dst[i+1]=sp[i]; }
            if (t==0) dst[0]=0.f;
        }
        __syncthreads();
        // SufE: inclusive suffix of 2^s1s
        #pragma unroll
        for (int v=0; v<2; ++v){ const int i=t+v*1024; bufB[i]=__builtin_amdgcn_exp2f(key[i]); }
        __syncthreads();
        {
            float *sp=bufB, *dp=bufC;
            for (int off=1; off<2048; off<<=1){
                #pragma unroll
                for (int v=0; v<2; ++v){
                    const int i=t+v*1024;
                    float x = sp[i];
                    if (i+off<2048) x += sp[i+off];
                    dp[i]=x;
                }
                __syncthreads();
                float* tmp=sp; sp=dp; dp=tmp;
            }
            float* dst = SufE + (size_t)b*SUFSTR;
            #pragma unroll
            for (int v=0; v<2; ++v){ const int i=t+v*1024; dst[i]=sp[i]; }
            if (t==0) dst[2048]=0.f;
        }
    }
}

// ---- K3: per (batch,chunk): Z/c1/c2 per sorted-j, theta per sorted-i,
//      chunk partial sums of c1*Wh / c2*Wh ----
__global__ __launch_bounds__(256) void k_scanA(const float* __restrict__ s1s,
                                               const float* __restrict__ s2s,
                                               const float* __restrict__ SufE,
                                               const float* __restrict__ PreA,
                                               const int* __restrict__ prm,
                                               const __hip_bfloat16* __restrict__ Whb,
                                               float* __restrict__ c1g,
                                               float* __restrict__ c2g,
                                               int* __restrict__ thg,
                                               float* __restrict__ chS,
                                               float* __restrict__ chT){
    const int blk = blockIdx.x;        // 256: b=blk&7 pins batch to XCD
    const int b = blk & 7, c = blk >> 3;
    const int t = threadIdx.x;
    __shared__ __align__(16) float s1l[2048], s2l[2048];
    __shared__ __align__(16) float sufl[2052], prel[2052];
    __shared__ float c1l[CH], c2l[CH];
    __shared__ int   permc[CH];
    __shared__ float red[2][2][128];

    {
        #pragma unroll
        for (int v=0; v<2; ++v){
            const int i=t+v*256;
            ((f32x4*)s1l)[i]  = ((const f32x4*)(s1s  + (size_t)b*Nn))[i];
            ((f32x4*)s2l)[i]  = ((const f32x4*)(s2s  + (size_t)b*Nn))[i];
            ((f32x4*)sufl)[i] = ((const f32x4*)(SufE + (size_t)b*SUFSTR))[i];
            ((f32x4*)prel)[i] = ((const f32x4*)(PreA + (size_t)b*SUFSTR))[i];
        }
        if (t==0){
            sufl[2048] = SufE[(size_t)b*SUFSTR + 2048];
            prel[2048] = PreA[(size_t)b*SUFSTR + 2048];
        }
        if (t<CH) permc[t] = prm[(size_t)b*Nn + c*CH + t];
    }
    __syncthreads();
    if (t < CH){
        const int q = c*CH + t;
        const float s2v = s2l[q];
        int lo=0, hi=Nn;                       // phi = lower_bound(s1s, -s2v)
        while (lo<hi){ const int mid=(lo+hi)>>1; if (s1l[mid] < -s2v) lo=mid+1; else hi=mid; }
        const float e1 = __builtin_amdgcn_exp2f(s2v);
        const float ea = __builtin_amdgcn_exp2f(ALPHA*s2v);
        const float Z  = e1*sufl[lo] + ea*prel[lo];
        const float iz = 1.f/Z;
        c1l[t] = e1*iz;  c2l[t] = ea*iz;
        c1g[(size_t)b*Nn + q] = c1l[t];
        c2g[(size_t)b*Nn + q] = c2l[t];
        // theta for sorted row r=q: lower_bound(s2s, -s1s[r])
        const float s1v = s1l[q];
        int lo2=0, hi2=Nn;
        while (lo2<hi2){ const int mid=(lo2+hi2)>>1; if (s2l[mid] < -s1v) lo2=mid+1; else hi2=mid; }
        thg[(size_t)b*Nn + q] = lo2;
    }
    __syncthreads();
    {
        const int qh = t>>7, d = t&127;
        float sA=0.f, sB=0.f;
        #pragma unroll 8
        for (int qq=0; qq<32; ++qq){
            const int ql = qh*32 + qq;
            const float w = bf2f(((const unsigned short*)Whb)[((size_t)b*Nn + permc[ql])*FOUT + d]);
            sA += c1l[ql]*w;
            sB += c2l[ql]*w;
        }
        red[0][qh][d]=sA; red[1][qh][d]=sB;
    }
    __syncthreads();
    if (t < 128)      chS[((size_t)b*NC + c)*128 + t]       = red[0][0][t] + red[0][1][t];
    else { const int d=t-128; chT[((size_t)b*NC + c)*128 + d] = red[1][0][d] + red[1][1][d]; }
}

// ---- K4: per (batch,chunk): local S/T scan (+cross-chunk carries), then
//      emit out rows whose theta falls in this chunk (contiguous in sorted-i) ----
__global__ __launch_bounds__(256) void k_scanOut(const float* __restrict__ s1s,
                                                 const int* __restrict__ ipr,
                                                 const int* __restrict__ prm,
                                                 const int* __restrict__ thg,
                                                 const float* __restrict__ c1g,
                                                 const float* __restrict__ c2g,
                                                 const float* __restrict__ chS,
                                                 const float* __restrict__ chT,
                                                 const __hip_bfloat16* __restrict__ Whb,
                                                 float* __restrict__ out){
    const int blk = blockIdx.x;        // 256: b=blk&7 pins batch to XCD
    const int b = blk & 7, c = blk >> 3;
    const int t = threadIdx.x;
    __shared__ __align__(16) float s1l[2048];
    __shared__ __align__(16) int   thl[2048];
    __shared__ __align__(16) int   iprl[2048];
    __shared__ int   permc[CH];
    __shared__ float c1l[CH], c2l[CH];
    __shared__ __align__(16) float whl[CH][128];
    __shared__ __align__(16) float Sloc[CH+1][128], Tloc[CH+1][128];

    {
        #pragma unroll
        for (int v=0; v<2; ++v){
            const int i=t+v*256;
            ((f32x4*)s1l)[i] = ((const f32x4*)(s1s + (size_t)b*Nn))[i];
            ((int4*)thl)[i]  = ((const int4*)(thg + (size_t)b*Nn))[i];
            ((int4*)iprl)[i] = ((const int4*)(ipr + (size_t)b*Nn))[i];
        }
        if (t<CH){
            permc[t] = prm[(size_t)b*Nn + c*CH + t];
            c1l[t]   = c1g[(size_t)b*Nn + c*CH + t];
            c2l[t]   = c2g[(size_t)b*Nn + c*CH + t];
        }
    }
    __syncthreads();
    {   // stage this chunk's Wh rows (perm-gathered, coalesced 256B/row)
        for (int v=0; v<32; ++v){
            const int e = v*256 + t;
            const int row = e>>7, d = e&127;
            whl[row][d] = bf2f(((const unsigned short*)Whb)[((size_t)b*Nn + permc[row])*FOUT + d]);
        }
    }
    float sc=0.f, tc=0.f;
    if (t < 128){   // cross-chunk carries (registers, thread t <-> d=t)
        #pragma unroll
        for (int cc=0; cc<NC; ++cc){
            if (cc > c) sc += chS[((size_t)b*NC + cc)*128 + t];
            if (cc < c) tc += chT[((size_t)b*NC + cc)*128 + t];
        }
    }
    __syncthreads();
    if (t < 128){   // build local S/T with carries folded in
        const int d = t;
        float run = sc;
        Sloc[CH][d] = run;
        #pragma unroll 8
        for (int p=CH-1; p>=0; --p){ run += c1l[p]*whl[p][d]; Sloc[p][d]=run; }
        float run2 = tc;
        Tloc[0][d] = run2;
        #pragma unroll 8
        for (int p=0; p<CH; ++p){ run2 += c2l[p]*whl[p][d]; Tloc[p+1][d]=run2; }
    }
    __syncthreads();
    // owned sorted-i range: theta in [L,U) ; thl is non-increasing in r
    const int U = (c==NC-1) ? (Nn+1) : (c*CH + CH);
    const int L = c*CH;
    int lo=0, hi=Nn;
    while (lo<hi){ const int mid=(lo+hi)>>1; if (thl[mid] < U) hi=mid; else lo=mid+1; }
    const int r_lo = lo;
    lo=0; hi=Nn;
    while (lo<hi){ const int mid=(lo+hi)>>1; if (thl[mid] < L) hi=mid; else lo=mid+1; }
    const int r_hi = lo;

    const int half = t>>7, d = t&127;
    for (int rr=r_lo; rr<r_hi; rr+=2){
        const int r = rr + half;
        if (r < r_hi){
            const int p = thl[r] - L;
            const float s1v = s1l[r];
            const float u1 = __builtin_amdgcn_exp2f(s1v);
            const float u2 = __builtin_amdgcn_exp2f(ALPHA*s1v);
            const float x = u1*Sloc[p][d] + u2*Tloc[p][d];
            out[((size_t)b*Nn + iprl[r])*FOUT + d] = x > 0.f ? x : expm1f(x);
        }
    }
}

extern "C" void kernel_launch(void* const* d_in, const int* in_sizes, int n_in,
                              void* d_out, int out_size, void* d_ws, size_t ws_size,
                              hipStream_t stream) {
    (void)in_sizes; (void)n_in; (void)out_size; (void)ws_size;
    const float* h = (const float*)d_in[0];
    const float* W = (const float*)d_in[1];
    const float* a = (const float*)d_in[2];
    float* out = (float*)d_out;

    float* ws   = (float*)d_ws;
    float* s1h  = ws;                        // 8*2048
    float* s2h  = s1h + Bb*Nn;
    float* s1s  = s2h + Bb*Nn;
    float* s2s  = s1s + Bb*Nn;
    float* SufE = s2s + Bb*Nn;               // 8*2052
    float* PreA = SufE + Bb*SUFSTR;
    float* c1g  = PreA + Bb*SUFSTR;
    float* c2g  = c1g + Bb*Nn;
    float* chS  = c2g + Bb*Nn;               // 8*32*128
    float* chT  = chS + Bb*NC*128;
    int*   thg  = (int*)(chT + Bb*NC*128);
    int*   prm  = thg + Bb*Nn;
    int*   ipr  = prm + Bb*Nn;
    __hip_bfloat16* Whb = (__hip_bfloat16*)(ipr + Bb*Nn);  // 4 MB

    k_wh     <<<dim3(Bb*Nn/32), dim3(256),  0, stream>>>(h, W, a, s1h, s2h, Whb);
    k_sort   <<<dim3(16),       dim3(1024), 0, stream>>>(s1h, s2h, s1s, s2s, ipr, prm, SufE, PreA);
    k_scanA  <<<dim3(Bb*NC),    dim3(256),  0, stream>>>(s1s, s2s, SufE, PreA, prm, Whb,
                                                         c1g, c2g, thg, chS, chT);
    k_scanOut<<<dim3(Bb*NC),    dim3(256),  0, stream>>>(s1s, ipr, prm, thg, c1g, c2g,
                                                         chS, chT, Whb, out);
}

// Round 6
// 124.814 us; speedup vs baseline: 1.0386x; 1.0386x over previous
//
#include <hip/hip_runtime.h>
#include <hip/hip_bf16.h>

// GAT layer: B=8, N=2048, Fin=256, Fout=128  (f32 in / f32 out)
// Wh = h@W ; s1 = Wh@a1 ; s2 = Wh@a2
// P[i,j] = softmax_i( lrelu(s1_i+s2_j) ) ; out = elu(P @ Wh)
//
// R19: rank-separable algorithm (validated in R18: passed, absmax 0.0625)
// with the 40us bitonic sort replaced:
//  - k_rank: rank-by-counting, barrier-free. 64-bit keys (sortable-u32<<11|idx)
//    -> bijective ranks; 256 blocks x 256 thr (2 thr/elem, each counts half
//    the keyspace via v_cmp_lt_u64 from LDS), shfl_xor combine, scatter.
//  - k_scan: one 8-block kernel: shfl-based prefix scans of 2^s1s / 2^(a*s1s)
//    (2 barriers/scan, not 11 Hillis-Steele stages), then phi-search -> Z ->
//    c1/c2 per j and theta-search per i. SufE/PreA stay in LDS (no global).
//  - k_chunk / k_out: R18's proven chunk-partial + scan-out kernels.
// Z_j     = 2^s2j * SufE[phi_j] + 2^(a*s2j) * PreA[phi_j]     (sorted s1)
// out[i,:]= 2^s1i * S[theta_i,:] + 2^(a*s1i) * T[theta_i,:]   (sorted s2)

#define ALPHA 0.2f
#define LOG2E 1.4426950408889634f
constexpr int Bb=8, Nn=2048, FIN=256, FOUT=128;
constexpr int NC=32, CH=64;          // chunks per batch, chunk size

typedef __attribute__((ext_vector_type(8))) short short8;
typedef __attribute__((ext_vector_type(4))) float f32x4;
typedef __attribute__((ext_vector_type(2))) unsigned long long u64x2;
typedef const __attribute__((address_space(1))) unsigned int* gptr_t;
typedef __attribute__((address_space(3))) unsigned int* lptr_t;

__device__ __forceinline__ unsigned short bfbits(float x){
    __hip_bfloat16 h = __float2bfloat16(x);
    return *(unsigned short*)&h;
}
__device__ __forceinline__ float bf2f(unsigned short u){
    unsigned int w = ((unsigned int)u) << 16;
    return *(float*)&w;
}

// ---- K1: Wh = h@W via MFMA -> s1,s2 (xLOG2E) + Wh bf16 row-major ----
__global__ __launch_bounds__(256) void k_wh(const float* __restrict__ h,
                                            const float* __restrict__ W,
                                            const float* __restrict__ a,
                                            float* __restrict__ s1h,
                                            float* __restrict__ s2h,
                                            __hip_bfloat16* __restrict__ Whb){
    const int blk = blockIdx.x;            // 512
    const int rowbase = blk * 32;
    const int t = threadIdx.x;
    const int wave = t>>6, lane = t&63;
    const int wm = wave & 1, wn = wave >> 1;
    const int lm = lane & 15, q = lane >> 4;

    __shared__ __align__(16) float hs[32*260];      // 33.3 KB
    __shared__ __align__(16) float tt2[32][132];    // 16.9 KB
    __shared__ float s1red[2][32], s2red[2][32];

    {   // DMA h rows: wave w stages rows w*8..w*8+7
        const float* srcbase = h + (size_t)rowbase*FIN;
        #pragma unroll
        for (int c = 0; c < 8; ++c){
            const int row = wave*8 + c;
            __builtin_amdgcn_global_load_lds(
                (gptr_t)(srcbase + (size_t)row*FIN + lane*4),
                (lptr_t)&hs[row*260], 16, 0, 0);
        }
    }
    __syncthreads();

    f32x4 acc[4];
    #pragma unroll
    for (int ntl = 0; ntl < 4; ++ntl) acc[ntl] = (f32x4){0.f,0.f,0.f,0.f};

    const float* hrow = &hs[(wm*16 + lm)*260];
    const float* Wq   = W + (size_t)(q*8)*FOUT + wn*64 + lm;
    #pragma unroll
    for (int kt = 0; kt < 8; ++kt){
        float av[8];
        *(float4*)&av[0] = *(const float4*)&hrow[kt*32 + q*8];
        *(float4*)&av[4] = *(const float4*)&hrow[kt*32 + q*8 + 4];
        short8 afr;
        #pragma unroll
        for (int e = 0; e < 8; ++e) afr[e] = (short)bfbits(av[e]);
        const float* Wkt = Wq + (size_t)kt*32*FOUT;
        #pragma unroll
        for (int ntl = 0; ntl < 4; ++ntl){
            const float* Wp = Wkt + ntl*16;
            short8 bfr;
            #pragma unroll
            for (int e = 0; e < 8; ++e) bfr[e] = (short)bfbits(Wp[(size_t)e*FOUT]);
            acc[ntl] = __builtin_amdgcn_mfma_f32_16x16x32_bf16(afr, bfr, acc[ntl], 0,0,0);
        }
    }

    {   // s1/s2 partials over this wave's 64 cols, lm-reduce
        float a1v[4], a2v[4];
        #pragma unroll
        for (int ntl = 0; ntl < 4; ++ntl){
            a1v[ntl] = a[wn*64 + ntl*16 + lm];
            a2v[ntl] = a[FOUT + wn*64 + ntl*16 + lm];
        }
        #pragma unroll
        for (int rg = 0; rg < 4; ++rg){
            float p1 = 0.f, p2 = 0.f;
            #pragma unroll
            for (int ntl = 0; ntl < 4; ++ntl){
                p1 += acc[ntl][rg]*a1v[ntl];
                p2 += acc[ntl][rg]*a2v[ntl];
            }
            #pragma unroll
            for (int m = 1; m < 16; m <<= 1){
                p1 += __shfl_xor(p1, m);
                p2 += __shfl_xor(p2, m);
            }
            if (lm == 0){
                s1red[wn][wm*16 + q*4 + rg] = p1;
                s2red[wn][wm*16 + q*4 + rg] = p2;
            }
        }
    }

    // acc -> tt2 f32 tile [row][d]  (C layout 16x16x32: row=wm*16+q*4+rg)
    #pragma unroll
    for (int ntl = 0; ntl < 4; ++ntl)
        #pragma unroll
        for (int rg = 0; rg < 4; ++rg)
            tt2[wm*16 + q*4 + rg][wn*64 + ntl*16 + lm] = acc[ntl][rg];
    __syncthreads();

    if (t < 32){
        s1h[rowbase + t] = (s1red[0][t] + s1red[1][t]) * LOG2E;
        s2h[rowbase + t] = (s2red[0][t] + s2red[1][t]) * LOG2E;
    }
    {   // coalesced bf16 row write: thread = (row: t>>3) x (16-d seg: t&7)
        const int row = t >> 3, seg = (t & 7) * 16;
        const float* src = &tt2[row][seg];
        short8 v0, v1;
        #pragma unroll
        for (int e = 0; e < 8; ++e){
            v0[e] = (short)bfbits(src[e]);
            v1[e] = (short)bfbits(src[e+8]);
        }
        short* dst = (short*)Whb + (size_t)(rowbase + row)*FOUT + seg;
        *(short8*)dst       = v0;
        *(short8*)(dst + 8) = v1;
    }
}

// ---- K2: rank-by-count sort. 256 blocks = 16 jobs x 16 segs.
// job = (batch, array); seg owns 128 elements; 2 threads/elem scan half
// the keyspace each. Bijective ranks via (value, index) 64-bit keys. ----
__global__ __launch_bounds__(256) void k_rank(const float* __restrict__ s1h,
                                              const float* __restrict__ s2h,
                                              float* __restrict__ s1s,
                                              float* __restrict__ s2s,
                                              int* __restrict__ ipr,
                                              int* __restrict__ prm){
    const int bb  = blockIdx.x;          // 256
    const int job = bb >> 4, seg = bb & 15;
    const bool isS1 = job >= 8;
    const int b = job & 7;
    const int t = threadIdx.x;
    __shared__ __align__(16) unsigned long long sk[2048];   // 16 KB

    const float* src = (isS1 ? s1h : s2h) + (size_t)b*Nn;
    {   // stage + build sortable keys: 256 thr x 2 f32x4 = 2048
        #pragma unroll
        for (int v = 0; v < 2; ++v){
            const int i4 = t + v*256;
            float4 f4 = ((const float4*)src)[i4];
            const int base = i4*4;
            #pragma unroll
            for (int e = 0; e < 4; ++e){
                unsigned int u = __float_as_uint(((const float*)&f4)[e]);
                u = (u & 0x80000000u) ? ~u : (u | 0x80000000u);
                sk[base+e] = (((unsigned long long)u) << 11) | (unsigned)(base+e);
            }
        }
    }
    __syncthreads();
    const int e    = seg*128 + (t >> 1);    // element this thread ranks
    const int half = t & 1;
    const unsigned long long x = sk[e];
    int cnt = 0;
    {
        const unsigned long long* p = &sk[half*1024];
        #pragma unroll 4
        for (int k = 0; k < 1024; k += 2){
            u64x2 kv = *(const u64x2*)&p[k];
            cnt += (kv[0] < x) + (kv[1] < x);
        }
    }
    const int rank = cnt + __shfl_xor(cnt, 1);
    if (half == 0){
        const unsigned int su = (unsigned int)(x >> 11);
        const float f = (su & 0x80000000u) ? __uint_as_float(su ^ 0x80000000u)
                                           : __uint_as_float(~su);
        float* kdst = (isS1 ? s1s : s2s) + (size_t)b*Nn;
        int*   pdst = (isS1 ? ipr : prm) + (size_t)b*Nn;
        kdst[rank] = f;
        pdst[rank] = e;
    }
}

// ---- K3: per batch (8 blocks x 1024): prefix scans of 2^s1s, 2^(a*s1s)
// in LDS (shfl scan, 2 barriers), then c1/c2 per j (phi-search) and
// theta per i. SufE(lo) = ET - preE[lo]; PreA(lo) = preA[lo]. ----
__global__ __launch_bounds__(1024) void k_scan(const float* __restrict__ s1s,
                                               const float* __restrict__ s2s,
                                               float* __restrict__ c1g,
                                               float* __restrict__ c2g,
                                               int* __restrict__ thg){
    const int b = blockIdx.x;            // 8
    const int t = threadIdx.x;
    const int lane = t & 63, w = t >> 6;     // 16 waves
    __shared__ __align__(16) float s1l[2048], s2l[2048];
    __shared__ __align__(16) float preE[2049], preA[2049];
    __shared__ float wt[2][16];

    if (t < 512) ((f32x4*)s1l)[t]      = ((const f32x4*)(s1s + (size_t)b*Nn))[t];
    else         ((f32x4*)s2l)[t-512]  = ((const f32x4*)(s2s + (size_t)b*Nn))[t-512];
    __syncthreads();

    // per-thread pair (2t, 2t+1)
    const float k0 = s1l[2*t], k1 = s1l[2*t+1];
    const float e0 = __builtin_amdgcn_exp2f(k0),       e1 = __builtin_amdgcn_exp2f(k1);
    const float a0 = __builtin_amdgcn_exp2f(ALPHA*k0), a1 = __builtin_amdgcn_exp2f(ALPHA*k1);
    float se = e0 + e1, sa = a0 + a1;
    #pragma unroll
    for (int off = 1; off < 64; off <<= 1){
        const float ve = __shfl_up(se, off);
        const float va = __shfl_up(sa, off);
        if (lane >= off){ se += ve; sa += va; }
    }
    if (lane == 63){ wt[0][w] = se; wt[1][w] = sa; }
    __syncthreads();
    if (t == 0){
        float rE = 0.f, rA = 0.f;
        for (int wv = 0; wv < 16; ++wv){
            rE += wt[0][wv]; wt[0][wv] = rE;
            rA += wt[1][wv]; wt[1][wv] = rA;
        }
    }
    __syncthreads();
    {
        const float offE = w ? wt[0][w-1] : 0.f;
        const float offA = w ? wt[1][w-1] : 0.f;
        const float exE = offE + se - (e0 + e1);    // exclusive before 2t
        const float exA = offA + sa - (a0 + a1);
        preE[2*t]   = exE;        preA[2*t]   = exA;
        preE[2*t+1] = exE + e0;   preA[2*t+1] = exA + a0;
        if (t == 0){ preE[2048] = wt[0][15]; preA[2048] = wt[1][15]; }
    }
    __syncthreads();
    const float ET = preE[2048];
    #pragma unroll
    for (int v = 0; v < 2; ++v){
        const int q = t + v*1024;
        {   // c1/c2 for sorted-j position q
            const float s2v = s2l[q];
            int lo = 0, hi = Nn;                 // phi = lower_bound(s1l, -s2v)
            while (lo < hi){ const int mid = (lo+hi)>>1; if (s1l[mid] < -s2v) lo = mid+1; else hi = mid; }
            const float ee = __builtin_amdgcn_exp2f(s2v);
            const float ea = __builtin_amdgcn_exp2f(ALPHA*s2v);
            const float Z  = ee*(ET - preE[lo]) + ea*preA[lo];
            const float iz = 1.f/Z;
            c1g[(size_t)b*Nn + q] = ee*iz;
            c2g[(size_t)b*Nn + q] = ea*iz;
        }
        {   // theta for sorted-i row q
            const float s1v = s1l[q];
            int lo = 0, hi = Nn;                 // lower_bound(s2l, -s1v)
            while (lo < hi){ const int mid = (lo+hi)>>1; if (s2l[mid] < -s1v) lo = mid+1; else hi = mid; }
            thg[(size_t)b*Nn + q] = lo;
        }
    }
}

// ---- K4: per (batch,chunk): chunk partial sums of c1*Wh / c2*Wh ----
__global__ __launch_bounds__(256) void k_chunk(const int* __restrict__ prm,
                                               const float* __restrict__ c1g,
                                               const float* __restrict__ c2g,
                                               const __hip_bfloat16* __restrict__ Whb,
                                               float* __restrict__ chS,
                                               float* __restrict__ chT){
    const int blk = blockIdx.x;        // 256: b=blk&7 pins batch to XCD
    const int b = blk & 7, c = blk >> 3;
    const int t = threadIdx.x;
    __shared__ int   permc[CH];
    __shared__ float c1l[CH], c2l[CH];
    __shared__ float red[2][2][128];

    if (t < CH){
        permc[t] = prm[(size_t)b*Nn + c*CH + t];
        c1l[t]   = c1g[(size_t)b*Nn + c*CH + t];
        c2l[t]   = c2g[(size_t)b*Nn + c*CH + t];
    }
    __syncthreads();
    {
        const int qh = t>>7, d = t&127;
        float sA = 0.f, sB = 0.f;
        #pragma unroll 8
        for (int qq = 0; qq < 32; ++qq){
            const int ql = qh*32 + qq;
            const float w = bf2f(((const unsigned short*)Whb)[((size_t)b*Nn + permc[ql])*FOUT + d]);
            sA += c1l[ql]*w;
            sB += c2l[ql]*w;
        }
        red[0][qh][d] = sA; red[1][qh][d] = sB;
    }
    __syncthreads();
    if (t < 128)      chS[((size_t)b*NC + c)*128 + t]        = red[0][0][t] + red[0][1][t];
    else { const int d = t-128; chT[((size_t)b*NC + c)*128 + d] = red[1][0][d] + red[1][1][d]; }
}

// ---- K5: per (batch,chunk): local S/T scan (+cross-chunk carries), then
//      emit out rows whose theta falls in this chunk (contiguous in sorted-i) ----
__global__ __launch_bounds__(256) void k_out(const float* __restrict__ s1s,
                                             const int* __restrict__ ipr,
                                             const int* __restrict__ prm,
                                             const int* __restrict__ thg,
                                             const float* __restrict__ c1g,
                                             const float* __restrict__ c2g,
                                             const float* __restrict__ chS,
                                             const float* __restrict__ chT,
                                             const __hip_bfloat16* __restrict__ Whb,
                                             float* __restrict__ out){
    const int blk = blockIdx.x;        // 256: b=blk&7 pins batch to XCD
    const int b = blk & 7, c = blk >> 3;
    const int t = threadIdx.x;
    __shared__ __align__(16) float s1l[2048];
    __shared__ __align__(16) int   thl[2048];
    __shared__ __align__(16) int   iprl[2048];
    __shared__ int   permc[CH];
    __shared__ float c1l[CH], c2l[CH];
    __shared__ __align__(16) float whl[CH][128];
    __shared__ __align__(16) float Sloc[CH+1][128], Tloc[CH+1][128];

    {
        #pragma unroll
        for (int v=0; v<2; ++v){
            const int i = t + v*256;
            ((f32x4*)s1l)[i] = ((const f32x4*)(s1s + (size_t)b*Nn))[i];
            ((int4*)thl)[i]  = ((const int4*)(thg + (size_t)b*Nn))[i];
            ((int4*)iprl)[i] = ((const int4*)(ipr + (size_t)b*Nn))[i];
        }
        if (t < CH){
            permc[t] = prm[(size_t)b*Nn + c*CH + t];
            c1l[t]   = c1g[(size_t)b*Nn + c*CH + t];
            c2l[t]   = c2g[(size_t)b*Nn + c*CH + t];
        }
    }
    __syncthreads();
    {   // stage this chunk's Wh rows (perm-gathered, coalesced 256B/row)
        for (int v = 0; v < 32; ++v){
            const int e = v*256 + t;
            const int row = e>>7, d = e&127;
            whl[row][d] = bf2f(((const unsigned short*)Whb)[((size_t)b*Nn + permc[row])*FOUT + d]);
        }
    }
    float sc = 0.f, tc = 0.f;
    if (t < 128){   // cross-chunk carries (registers, thread t <-> d=t)
        #pragma unroll
        for (int cc = 0; cc < NC; ++cc){
            if (cc > c) sc += chS[((size_t)b*NC + cc)*128 + t];
            if (cc < c) tc += chT[((size_t)b*NC + cc)*128 + t];
        }
    }
    __syncthreads();
    if (t < 128){   // build local S/T with carries folded in
        const int d = t;
        float run = sc;
        Sloc[CH][d] = run;
        #pragma unroll 8
        for (int p = CH-1; p >= 0; --p){ run += c1l[p]*whl[p][d]; Sloc[p][d] = run; }
        float run2 = tc;
        Tloc[0][d] = run2;
        #pragma unroll 8
        for (int p = 0; p < CH; ++p){ run2 += c2l[p]*whl[p][d]; Tloc[p+1][d] = run2; }
    }
    __syncthreads();
    // owned sorted-i range: theta in [L,U) ; thl is non-increasing in r
    const int U = (c == NC-1) ? (Nn+1) : (c*CH + CH);
    const int L = c*CH;
    int lo = 0, hi = Nn;
    while (lo < hi){ const int mid = (lo+hi)>>1; if (thl[mid] < U) hi = mid; else lo = mid+1; }
    const int r_lo = lo;
    lo = 0; hi = Nn;
    while (lo < hi){ const int mid = (lo+hi)>>1; if (thl[mid] < L) hi = mid; else lo = mid+1; }
    const int r_hi = lo;

    const int half = t>>7, d = t&127;
    for (int rr = r_lo; rr < r_hi; rr += 2){
        const int r = rr + half;
        if (r < r_hi){
            const int p = thl[r] - L;
            const float s1v = s1l[r];
            const float u1 = __builtin_amdgcn_exp2f(s1v);
            const float u2 = __builtin_amdgcn_exp2f(ALPHA*s1v);
            const float x = u1*Sloc[p][d] + u2*Tloc[p][d];
            out[((size_t)b*Nn + iprl[r])*FOUT + d] = x > 0.f ? x : expm1f(x);
        }
    }
}

extern "C" void kernel_launch(void* const* d_in, const int* in_sizes, int n_in,
                              void* d_out, int out_size, void* d_ws, size_t ws_size,
                              hipStream_t stream) {
    (void)in_sizes; (void)n_in; (void)out_size; (void)ws_size;
    const float* h = (const float*)d_in[0];
    const float* W = (const float*)d_in[1];
    const float* a = (const float*)d_in[2];
    float* out = (float*)d_out;

    float* ws   = (float*)d_ws;
    float* s1h  = ws;                        // 8*2048 f32 each
    float* s2h  = s1h + Bb*Nn;
    float* s1s  = s2h + Bb*Nn;
    float* s2s  = s1s + Bb*Nn;
    float* c1g  = s2s + Bb*Nn;
    float* c2g  = c1g + Bb*Nn;
    float* chS  = c2g + Bb*Nn;               // 8*32*128
    float* chT  = chS + Bb*NC*128;
    int*   thg  = (int*)(chT + Bb*NC*128);
    int*   prm  = thg + Bb*Nn;
    int*   ipr  = prm + Bb*Nn;
    __hip_bfloat16* Whb = (__hip_bfloat16*)(ipr + Bb*Nn);  // 4 MB

    k_wh   <<<dim3(Bb*Nn/32), dim3(256),  0, stream>>>(h, W, a, s1h, s2h, Whb);
    k_rank <<<dim3(256),      dim3(256),  0, stream>>>(s1h, s2h, s1s, s2s, ipr, prm);
    k_scan <<<dim3(Bb),       dim3(1024), 0, stream>>>(s1s, s2s, c1g, c2g, thg);
    k_chunk<<<dim3(Bb*NC),    dim3(256),  0, stream>>>(prm, c1g, c2g, Whb, chS, chT);
    k_out  <<<dim3(Bb*NC),    dim3(256),  0, stream>>>(s1s, ipr, prm, thg, c1g, c2g,
                                                       chS, chT, Whb, out);
}

// Round 7
// 99.239 us; speedup vs baseline: 1.3063x; 1.2577x over previous
//
#include <hip/hip_runtime.h>
#include <hip/hip_bf16.h>

// GAT layer: B=8, N=2048, Fin=256, Fout=128  (f32 in / f32 out)
// Wh = h@W ; s1 = Wh@a1 ; s2 = Wh@a2
// P[i,j] = softmax_i( lrelu(s1_i+s2_j) ) ; out = elu(P @ Wh)
// R20 = R14 verbatim (session best: 100.9us). Rationale: R13-R16 (four
// structurally different O(N^2) pipelines) span 100.9-105.2us; R18/R19's
// validated O(N logN + N D) scan algorithm lands 124.8-129.6 with no
// per-kernel attribution available to fix it. Fixed harness cost (268MB
// poison fill ~43.5us + node gaps) dominates; restoring the best config.
//      k_pv: 32-row waves via mfma_f32_32x32x16_bf16, 64-row/512-thread
//      blocks, 8 waves = 2 row-groups x 4 j-quarters, each quarter a
//      private double-buffered supertile DMA stream (Bs[2][4][16KB]).
//      WhT supertile 16B unit u = (s*4+nt)*64 + l5*32 + col.

#define ALPHA 0.2f
#define LOG2E 1.4426950408889634f
constexpr int Bb=8, Nn=2048, FIN=256, FOUT=128;

typedef __attribute__((ext_vector_type(8))) short short8;
typedef __attribute__((ext_vector_type(4))) float f32x4;
typedef __attribute__((ext_vector_type(16))) float f32x16;
typedef const __attribute__((address_space(1))) unsigned int* gptr_t;
typedef __attribute__((address_space(3))) unsigned int* lptr_t;

__device__ __forceinline__ float lrelu(float x){ return fmaxf(x, ALPHA*x); }
__device__ __forceinline__ unsigned short bfbits(float x){
    __hip_bfloat16 h = __float2bfloat16(x);
    return *(unsigned short*)&h;
}

// ---- K0: WT_t[kt][n][32] bf16 from W f32 ----
__global__ __launch_bounds__(256) void k_prep(const float* __restrict__ W,
                                              __hip_bfloat16* __restrict__ WTt){
    const int idx = blockIdx.x*256 + threadIdx.x;   // 32 blocks
    #pragma unroll
    for (int v = 0; v < 4; ++v){
        const int widx = idx + v*8192;
        const int kk = widx & 31, n = (widx>>5)&127, kt = widx>>12;
        WTt[widx] = __float2bfloat16(W[(kt*32+kk)*FOUT + n]);
    }
}

// ---- K1: Wh = h@W via MFMA -> s1,s2 (xLOG2E), WhT supertiles for k_pv ----
// h DMA-staged to LDS (row stride 260 f32 = 1040 B, minimal-round banks).
__global__ __launch_bounds__(256) void k_wh(const float* __restrict__ h,
                                            const float* __restrict__ a,
                                            const __hip_bfloat16* __restrict__ WTt,
                                            float* __restrict__ s1,
                                            float* __restrict__ s2,
                                            __hip_bfloat16* __restrict__ WhT){
    const int blk = blockIdx.x;            // 512
    const int rowbase = blk * 32;
    const int b = blk >> 6;
    const int jt = (rowbase & (Nn-1)) >> 5;     // 64 32-row tiles per batch
    const int t = threadIdx.x;
    const int wave = t>>6, lane = t&63;
    const int wm = wave & 1, wn = wave >> 1;
    const int lm = lane & 15, q = lane >> 4;

    __shared__ __align__(16) float hs[32*260];      // 33.3 KB, stride 260
    __shared__ unsigned short tt[FOUT*40];          // 10.2 KB, [d][row] pad 40
    __shared__ float s1red[2][32], s2red[2][32];

    {   // DMA h rows: wave w stages rows w*8..w*8+7 (1 KB per instr per row)
        const float* srcbase = h + (size_t)rowbase*FIN;
        #pragma unroll
        for (int c = 0; c < 8; ++c){
            const int row = wave*8 + c;
            __builtin_amdgcn_global_load_lds(
                (gptr_t)(srcbase + (size_t)row*FIN + lane*4),
                (lptr_t)&hs[row*260], 16, 0, 0);
        }
    }
    __syncthreads();   // drains DMA (compiler emits vmcnt(0) before barrier)

    f32x4 acc[4];
    #pragma unroll
    for (int ntl = 0; ntl < 4; ++ntl) acc[ntl] = (f32x4){0.f,0.f,0.f,0.f};

    const float* hrow = &hs[(wm*16 + lm)*260];
    const short* Wt = (const short*)WTt;
    #pragma unroll
    for (int kt = 0; kt < 8; ++kt){
        float av[8];
        *(float4*)&av[0] = *(const float4*)&hrow[kt*32 + q*8];
        *(float4*)&av[4] = *(const float4*)&hrow[kt*32 + q*8 + 4];
        short8 afr;
        #pragma unroll
        for (int e = 0; e < 8; ++e) afr[e] = (short)bfbits(av[e]);
        #pragma unroll
        for (int ntl = 0; ntl < 4; ++ntl){
            const short8 bfr = *(const short8*)(Wt + ((kt*128 + wn*64 + ntl*16 + lm)*32 + q*8));
            acc[ntl] = __builtin_amdgcn_mfma_f32_16x16x32_bf16(afr, bfr, acc[ntl], 0,0,0);
        }
    }

    {   // s1/s2 partials over this wave's 64 cols, lm-reduce
        float a1v[4], a2v[4];
        #pragma unroll
        for (int ntl = 0; ntl < 4; ++ntl){
            a1v[ntl] = a[wn*64 + ntl*16 + lm];
            a2v[ntl] = a[FOUT + wn*64 + ntl*16 + lm];
        }
        #pragma unroll
        for (int rg = 0; rg < 4; ++rg){
            float p1 = 0.f, p2 = 0.f;
            #pragma unroll
            for (int ntl = 0; ntl < 4; ++ntl){
                p1 += acc[ntl][rg]*a1v[ntl];
                p2 += acc[ntl][rg]*a2v[ntl];
            }
            #pragma unroll
            for (int m = 1; m < 16; m <<= 1){
                p1 += __shfl_xor(p1, m);
                p2 += __shfl_xor(p2, m);
            }
            if (lm == 0){
                s1red[wn][wm*16 + q*4 + rg] = p1;
                s2red[wn][wm*16 + q*4 + rg] = p2;
            }
        }
    }

    // C -> tt [d][row]
    #pragma unroll
    for (int ntl = 0; ntl < 4; ++ntl){
        ushort4 u;
        u.x = bfbits(acc[ntl][0]); u.y = bfbits(acc[ntl][1]);
        u.z = bfbits(acc[ntl][2]); u.w = bfbits(acc[ntl][3]);
        *(ushort4*)&tt[(wn*64 + ntl*16 + lm)*40 + wm*16 + q*4] = u;
    }
    __syncthreads();

    if (t < 32){
        s1[rowbase + t] = (s1red[0][t] + s1red[1][t]) * LOG2E;
        s2[rowbase + t] = (s2red[0][t] + s2red[1][t]) * LOG2E;
    }
    {   // WhT supertile write (64j x 128d = 16 KB), 32x32x16-B-frag layout:
        // 16B unit u = (s*4+nt)*64 + l5*32 + col; s = jj>>4, l5 = (jj>>3)&1,
        // e = jj&7 packed inside the unit; nt = d>>5, col = d&31.
        const int d = t >> 1, jsub16 = t & 1;
        const unsigned short* src = &tt[d*40 + jsub16*16];
        short8 v0 = *(const short8*)src;         // jj = base+0..7   (l5=0)
        short8 v1 = *(const short8*)(src + 8);   // jj = base+8..15  (l5=1)
        const int s  = (jt & 1)*2 + jsub16;
        const int nt = d >> 5, col = d & 31;
        const int u0 = (s*4 + nt)*64 + col;
        short* Wo = (short*)WhT;
        const size_t tb = ((size_t)(b*32 + (jt >> 1)))*8192;   // supertile base (shorts)
        *(short8*)&Wo[tb + (size_t)u0*8]      = v0;
        *(short8*)&Wo[tb + (size_t)(u0+32)*8] = v1;
    }
}

// ---- K2: l2z[b,j] = -log2(Z_j)  (no max shift needed: |z|<=~17) ----
__global__ __launch_bounds__(256) void k_z(const float* __restrict__ s1,
                                           const float* __restrict__ s2,
                                           float* __restrict__ l2z){
    const int b  = blockIdx.x >> 6;      // 512 blocks, 32 j each
    const int jt = blockIdx.x & 63;
    const int t  = threadIdx.x;
    const int jj = t & 31, part = t >> 5;
    const int j  = jt*32 + jj;
    __shared__ float s1s[Nn];
    __shared__ float red[8][33];

    {
        const float4* g = (const float4*)(s1 + (size_t)b*Nn);
        float4* p = (float4*)s1s;
        #pragma unroll
        for (int v0 = 0; v0 < 2; ++v0){ const int v = t + v0*256; p[v] = g[v]; }
    }
    __syncthreads();
    const float s2j = s2[b*Nn + j];
    float sum = 0.f;
    const float4* s4 = (const float4*)&s1s[part*256];
    #pragma unroll 4
    for (int v = 0; v < 64; ++v){
        float x[4]; *(float4*)x = s4[v];
        sum += __builtin_amdgcn_exp2f(lrelu(x[0]+s2j))
             + __builtin_amdgcn_exp2f(lrelu(x[1]+s2j))
             + __builtin_amdgcn_exp2f(lrelu(x[2]+s2j))
             + __builtin_amdgcn_exp2f(lrelu(x[3]+s2j));
    }
    red[part][jj] = sum;
    __syncthreads();
    if (part == 0){
        float Z = 0.f;
        #pragma unroll
        for (int p = 0; p < 8; ++p) Z += red[p][jj];
        l2z[b*Nn + j] = -__builtin_amdgcn_logf(Z);   // v_log_f32 = log2
    }
}

// ---- K3: out = elu(P @ Wh), 32x32x16 MFMA, 64 rows/block, 8 waves ----
// waves = (wr: 2 row-groups of 32) x (kh: 4 j-quarters of 512).
// Each quarter double-buffers its own 16 KB supertile stream via DMA.
__global__ __launch_bounds__(512, 2) void k_pv(const float* __restrict__ s1,
                                               const float* __restrict__ s2,
                                               const float* __restrict__ l2z,
                                               const __hip_bfloat16* __restrict__ WhT,
                                               float* __restrict__ out){
    const int blk   = blockIdx.x;          // 256 (b = blk&7 pins batch to XCD)
    const int b     = blk & 7;
    const int ibase = (blk >> 3) * 64;
    const int t     = threadIdx.x;
    const int wave  = t >> 6, lane = t & 63;
    const int wr = wave & 1, kh = wave >> 1;
    const int il = lane & 31, l5 = lane >> 5;

    __shared__ float s2s[Nn], lzs[Nn];                 // 16 KB
    __shared__ unsigned short Bs[2][4][8192];          // 128 KB: dbuf x quarter x 16KB

    {   // stage s2/lz once (512 thr x 16B = full 8 KB each)
        const float4* g1 = (const float4*)(s2  + (size_t)b*Nn);
        const float4* g2 = (const float4*)(l2z + (size_t)b*Nn);
        ((float4*)s2s)[t] = g1[t];
        ((float4*)lzs)[t] = g2[t];
    }

    const float s1a = s1[(size_t)b*Nn + ibase + wr*32 + il];

    f32x16 acc[4];
    #pragma unroll
    for (int nt = 0; nt < 4; ++nt)
        #pragma unroll
        for (int e = 0; e < 16; ++e) acc[nt][e] = 0.f;

    const char* Wtb = (const char*)WhT + (size_t)b*32*16384;
    const int laneoff = wr*8192 + lane*16;

    {   // preload quarter's supertile 0 into buf 0
        const char* src = Wtb + (size_t)(kh*8)*16384 + laneoff;
        unsigned short* dst = &Bs[0][kh][wr*4096];
        #pragma unroll
        for (int c = 0; c < 8; ++c)
            __builtin_amdgcn_global_load_lds((gptr_t)(src + c*1024),
                                             (lptr_t)(dst + c*512), 16, 0, 0);
    }

    int buf = 0;
    for (int it = 0; it < 8; ++it){
        __syncthreads();
        if (it + 1 < 8){
            const char* src = Wtb + (size_t)(kh*8 + it + 1)*16384 + laneoff;
            unsigned short* dst = &Bs[buf^1][kh][wr*4096];
            #pragma unroll
            for (int c = 0; c < 8; ++c)
                __builtin_amdgcn_global_load_lds((gptr_t)(src + c*1024),
                                                 (lptr_t)(dst + c*512), 16, 0, 0);
        }
        const char* tile = (const char*)&Bs[buf][kh][0];
        #pragma unroll
        for (int s = 0; s < 4; ++s){
            short8 bfr[4];
            #pragma unroll
            for (int nt = 0; nt < 4; ++nt)
                bfr[nt] = *(const short8*)(tile + ((s*4 + nt)*64 + lane)*16);

            const int jb = kh*512 + it*64 + s*16 + l5*8;
            float sarr[8], larr[8];
            *(float4*)&sarr[0] = *(const float4*)&s2s[jb];
            *(float4*)&sarr[4] = *(const float4*)&s2s[jb+4];
            *(float4*)&larr[0] = *(const float4*)&lzs[jb];
            *(float4*)&larr[4] = *(const float4*)&lzs[jb+4];
            short8 afa;
            #pragma unroll
            for (int e = 0; e < 8; ++e){
                const float z = s1a + sarr[e];
                afa[e] = (short)bfbits(__builtin_amdgcn_exp2f(fmaxf(z, ALPHA*z) + larr[e]));
            }
            #pragma unroll
            for (int nt = 0; nt < 4; ++nt)
                acc[nt] = __builtin_amdgcn_mfma_f32_32x32x16_bf16(afa, bfr[nt], acc[nt], 0,0,0);
        }
        buf ^= 1;
    }

    // combine 4 j-quarters through LDS (reuse Bs), ELU, store.
    // region(p, wr) = comb + (p*2+wr)*32*132 : kh0->r(0), kh1->r(1),
    // kh2 += r(0), kh3 += r(1); final pass sums r(0)+r(1).
    __syncthreads();
    float* comb = (float*)&Bs[0][0][0];    // 4 x 32x132 f32 = 67.6 KB
    if (kh < 2){
        float* cb = comb + (size_t)(kh*2 + wr)*(32*132);
        #pragma unroll
        for (int nt = 0; nt < 4; ++nt)
            #pragma unroll
            for (int r = 0; r < 16; ++r){
                const int row = (r&3) + 8*(r>>2) + 4*l5;
                cb[row*132 + nt*32 + il] = acc[nt][r];
            }
    }
    __syncthreads();
    if (kh >= 2){
        float* cb = comb + (size_t)((kh-2)*2 + wr)*(32*132);
        #pragma unroll
        for (int nt = 0; nt < 4; ++nt)
            #pragma unroll
            for (int r = 0; r < 16; ++r){
                const int row = (r&3) + 8*(r>>2) + 4*l5;
                cb[row*132 + nt*32 + il] += acc[nt][r];
            }
    }
    __syncthreads();
    {   // all 512 threads: thread = (rgrp: 4 rows) x (c4: 4 cols), coalesced f32x4
        const int rgrp = t >> 5, c4 = (t & 31)*4;
        #pragma unroll
        for (int rr = 0; rr < 4; ++rr){
            const int row = rgrp*4 + rr;
            const int wrr = row >> 5, rin = row & 31;
            const float* r0 = comb + (size_t)(wrr)*(32*132)       + rin*132 + c4;
            const float* r1 = comb + (size_t)(2 + wrr)*(32*132)   + rin*132 + c4;
            float4 v0 = *(const float4*)r0, v1 = *(const float4*)r1;
            float o[4];
            #pragma unroll
            for (int e = 0; e < 4; ++e){
                const float x = ((const float*)&v0)[e] + ((const float*)&v1)[e];
                o[e] = x > 0.f ? x : expm1f(x);
            }
            *(float4*)&out[((size_t)(b*Nn + ibase + row))*FOUT + c4] = *(float4*)o;
        }
    }
}

extern "C" void kernel_launch(void* const* d_in, const int* in_sizes, int n_in,
                              void* d_out, int out_size, void* d_ws, size_t ws_size,
                              hipStream_t stream) {
    (void)in_sizes; (void)n_in; (void)out_size; (void)ws_size;
    const float* h = (const float*)d_in[0];
    const float* W = (const float*)d_in[1];
    const float* a = (const float*)d_in[2];
    float* out = (float*)d_out;

    float* ws    = (float*)d_ws;
    float* s1    = ws;                    // 16384
    float* s2    = s1 + Bb*Nn;            // 16384
    float* l2z   = s2 + Bb*Nn;            // 16384
    __hip_bfloat16* WTt = (__hip_bfloat16*)(l2z + Bb*Nn);  // 64 KB
    __hip_bfloat16* WhT = WTt + 32768;                     // 4 MB supertiles

    k_prep<<<dim3(32),        dim3(256), 0, stream>>>(W, WTt);
    k_wh  <<<dim3(Bb*Nn/32),  dim3(256), 0, stream>>>(h, a, WTt, s1, s2, WhT);
    k_z   <<<dim3(Bb*64),     dim3(256), 0, stream>>>(s1, s2, l2z);
    k_pv  <<<dim3(Bb*Nn/64),  dim3(512), 0, stream>>>(s1, s2, l2z, WhT, out);
}